// Round 13
// baseline (76.665 us; speedup 1.0000x reference)
//
#include <hip/hip_runtime.h>
#include <hip/hip_bf16.h>
#include <math.h>
#include <stdint.h>

#define Bb 16
#define Tt 28
#define Nn 2048
#define Hh 32
#define LAGS 8
#define LN_EPS 1e-5f
#define PSTR 40                      // P row stride (shorts)
#define LOG2E 1.4426950408889634f

typedef float f4 __attribute__((ext_vector_type(4)));
typedef short s8v __attribute__((ext_vector_type(8)));
typedef unsigned short u16x4 __attribute__((ext_vector_type(4)));
typedef unsigned short u16x8 __attribute__((ext_vector_type(8)));

__device__ __forceinline__ float b2f(unsigned short u) {
    union { unsigned uu; float ff; } x; x.uu = ((unsigned)u) << 16; return x.ff;
}
__device__ __forceinline__ unsigned short f2b(float f) {
    unsigned u = __float_as_uint(f);
    u += 0x7FFFu + ((u >> 16) & 1u);   // RNE
    return (unsigned short)(u >> 16);
}
__device__ __forceinline__ unsigned packbf2(float lo, float hi) {
    __hip_bfloat162 h = __float22bfloat162_rn(make_float2(lo, hi));
    union { __hip_bfloat162 h2; unsigned u; } c; c.h2 = h; return c.u;
}
__device__ __forceinline__ float exp2i(float x) {   // native 2^x, single instr
    float r; asm("v_exp_f32 %0, %1" : "=v"(r) : "v"(x)); return r;
}
__device__ __forceinline__ void gld16(const void* g, void* l) {
    __builtin_amdgcn_global_load_lds(
        (const __attribute__((address_space(1))) unsigned int*)g,
        (__attribute__((address_space(3))) unsigned int*)l, 16, 0, 0);
}

// ---------- adj fp32 -> bf16 scaled by geo*5*log2e, fragment-tile layout ----------
// adjF[((n>>4)*512 + (m>>2))*64 + (n&15)*4 + (m&3)]
__global__ void k_adjprep(const float* __restrict__ adj, const float* __restrict__ geo_w,
                          unsigned short* __restrict__ adjF) {
    __shared__ float T[16][516];
    float geo = 1.f / (1.f + __expf(-geo_w[0]));
    float cg = geo * 5.f * LOG2E;
    int tid = threadIdx.x;
    int g = blockIdx.x >> 2, q = blockIdx.x & 3;
    int n0 = g * 16, m0 = q * 512;
    #pragma unroll
    for (int r = 0; r < 16; ++r) {
        T[r][tid] = adj[(size_t)(n0 + r) * Nn + m0 + tid];
        T[r][tid + 256] = adj[(size_t)(n0 + r) * Nn + m0 + tid + 256];
    }
    __syncthreads();
    unsigned short* region = adjF + ((size_t)g * 512 + q * 128) * 64;
    #pragma unroll
    for (int i = 0; i < 4; ++i) {
        int e0 = (i * 256 + tid) * 8;
        u16x8 w;
        #pragma unroll
        for (int j = 0; j < 8; ++j) {
            int e = e0 + j;
            int mq = e >> 6, nl = (e >> 2) & 15, mm = e & 3;
            w[j] = f2b(cg * T[nl][mq * 4 + mm]);
        }
        *(u16x8*)(region + e0) = w;
    }
}

// ---------------- delayed signal (f32) ----------------
__global__ void k_delayed(const float* __restrict__ x,
                          const float* __restrict__ dlog,
                          float* __restrict__ dsg) {
    int idx = blockIdx.x * blockDim.x + threadIdx.x; // over B*N
    float w[LAGS];
    float m = -1e30f;
    #pragma unroll
    for (int t = 0; t < LAGS; ++t) m = fmaxf(m, dlog[t]);
    float s = 0.f;
    #pragma unroll
    for (int t = 0; t < LAGS; ++t) { w[t] = __expf(dlog[t] - m); s += w[t]; }
    float inv = 1.f / s;
    if (idx >= Bb * Nn) return;
    int b = idx / Nn, n = idx % Nn;
    float acc = 0.f;
    #pragma unroll
    for (int t = 0; t < LAGS; ++t)
        acc += (w[t] * inv) * x[(size_t)b * Tt * Nn + (size_t)(Tt - 1 - t) * Nn + n];
    dsg[idx] = acc;
}

// ---------- fused QKV: Q row-major pre-scaled by cs*log2e; K,V fragment layouts ----
// Kf[((b*128 + (m>>4))*4 + (k>>3))*16 + (m&15)][8]  (k&7 inner)  -> 65536 shorts/batch
// Vf[((b*64 + (m>>5))*4 + ((m>>3)&3))*32 + h][8]    (m&7 inner)  -> 65536 shorts/batch
__global__ void k_qkv(const float* __restrict__ feat,
                      const float* __restrict__ Wq, const float* __restrict__ bq,
                      const float* __restrict__ Wk, const float* __restrict__ bk,
                      const float* __restrict__ Wv, const float* __restrict__ bv,
                      const float* __restrict__ geo_w,
                      unsigned short* __restrict__ Qbf, unsigned short* __restrict__ Kf,
                      unsigned short* __restrict__ Vf) {
    __shared__ float WqT[Hh][Hh + 1], WkT[Hh][Hh + 1], WvT[Hh][Hh + 1];
    __shared__ float f[8][Hh];
    __shared__ __align__(16) unsigned short VT8[Hh][8];
    int tid = threadIdx.x;
    for (int i = tid; i < Hh * Hh; i += 256) {
        int h = i >> 5, k = i & 31;
        WqT[k][h] = Wq[i];
        WkT[k][h] = Wk[i];
        WvT[k][h] = Wv[i];
    }
    float geo = 1.f / (1.f + __expf(-geo_w[0]));
    float csL = (1.f - geo) * 0.17677669529663687f * LOG2E;
    int n0 = blockIdx.x * 8;
    f[tid >> 5][tid & 31] = feat[(size_t)n0 * Hh + tid];
    __syncthreads();
    int lr = tid >> 5, h = tid & 31;
    float aq = bq[h], ak = bk[h], av = bv[h];
    #pragma unroll
    for (int k = 0; k < Hh; ++k) {
        float fv = f[lr][k];
        aq += fv * WqT[k][h];
        ak += fv * WkT[k][h];
        av += fv * WvT[k][h];
    }
    Qbf[(size_t)(n0 + lr) * Hh + h] = f2b(aq * csL);
    int b = n0 >> 11, mloc = (n0 & 2047) + lr;
    size_t kaddr = ((((size_t)b * 128 + (mloc >> 4)) * 4 + (h >> 3)) * 16 + (mloc & 15)) * 8 + (h & 7);
    Kf[kaddr] = f2b(ak);
    VT8[h][lr] = f2b(av);
    __syncthreads();
    if (tid < 32) {
        int mloc0 = n0 & 2047;
        size_t vaddr = ((((size_t)b * 64 + (mloc0 >> 5)) * 4 + ((mloc0 >> 3) & 3)) * 32 + tid) * 8;
        *(u16x8*)(Vf + vaddr) = *(const u16x8*)&VT8[tid][0];
    }
}

// ---------------- MFMA attention: async LDS-staged, 1 barrier/chunk ---------------
// 4 waves/block, 32 n-cols, wave wh owns 32-m quarter of each 128-chunk.
// Stage K(8K)+V(8K)+adj(8K) per chunk via global_load_lds (6 per thread, no
// divergence, linear<->linear). Scores: mfma(K,Qs,C=adj) -> v_exp_f32 -> P -> PV.
__global__ __launch_bounds__(256)
void k_attn(const unsigned short* __restrict__ Qbf,
            const unsigned short* __restrict__ Kf,
            const unsigned short* __restrict__ Vf,
            const unsigned short* __restrict__ adjF,
            const float* __restrict__ dsg,
            const float* __restrict__ feat,
            unsigned short* __restrict__ comb) {
    __shared__ __align__(16) unsigned short Sg[2][12288];   // [buf]: K 4096 | V 4096 | adj 4096 shorts
    __shared__ __align__(16) unsigned short Pt[4][32 * PSTR]; // 10240 B; reused as merge scratch

    int tid = threadIdx.x;
    int wid = tid >> 6, lane = tid & 63;
    int nl = lane & 15, g4 = lane >> 4;
    int wh = wid;

    // XCD-partitioned swizzle: xcd = bid&7 -> (n-quarter = xcd>>1, batch-half = xcd&1)
    int bid = blockIdx.x;
    int xcd = bid & 7, r = bid >> 3;            // r: 0..127
    int b = ((xcd & 1) << 3) + (r & 7);
    int nt32 = ((xcd >> 1) << 4) + (r >> 3);    // 0..63
    int n0w = nt32 * 32;

    // Q B-fragments (col = n = nl, k = g4*8+j); Q pre-scaled by cs*log2e
    s8v qf[2];
    #pragma unroll
    for (int nt = 0; nt < 2; ++nt)
        qf[nt] = *(const s8v*)(Qbf + (((size_t)b * Nn + n0w + nt * 16 + nl) << 5) + g4 * 8);

    f4 pacc[2][2];
    #pragma unroll
    for (int nt = 0; nt < 2; ++nt)
        #pragma unroll
        for (int t = 0; t < 2; ++t) pacc[nt][t] = (f4){0.f, 0.f, 0.f, 0.f};
    float ps[2] = {0.f, 0.f}, prop[2] = {0.f, 0.f};

    const unsigned short* Kg0 = Kf + (size_t)b * 65536;            // chunk c at +c*4096
    const unsigned short* Vg0 = Vf + (size_t)b * 65536;            // chunk c at +c*4096
    const unsigned short* Aa0 = adjF + ((size_t)(nt32 * 2)) * 32768;     // chunk c at +c*2048
    const unsigned short* Ab0 = adjF + ((size_t)(nt32 * 2 + 1)) * 32768;
    const float* dsb = dsg + (size_t)b * Nn;
    unsigned short* Pw = Pt[wid];

    // stage chunk c into buffer buf: 1536 granules of 16B, 6 per thread, uniform mask
    auto stage = [&](int buf, int c) {
        const unsigned short* Kg = Kg0 + (size_t)c * 4096;
        const unsigned short* Vg = Vg0 + (size_t)c * 4096;
        const unsigned short* Aa = Aa0 + (size_t)c * 2048;
        const unsigned short* Ab = Ab0 + (size_t)c * 2048;
        unsigned short* L = &Sg[buf][0];
        #pragma unroll
        for (int i = 0; i < 6; ++i) {
            int g = i * 256 + wid * 64 + lane;       // region-aligned 64-lane windows
            const unsigned short* src;
            if (g < 512)       src = Kg + g * 8;
            else if (g < 1024) src = Vg + (g - 512) * 8;
            else if (g < 1280) src = Aa + (g - 1024) * 8;
            else               src = Ab + (g - 1280) * 8;
            gld16(src, L + (i * 256 + wid * 64) * 8);
        }
    };

    auto mkC = [&](u16x4 av) -> f4 {
        f4 C;
        C[0] = b2f(av[0]); C[1] = b2f(av[1]); C[2] = b2f(av[2]); C[3] = b2f(av[3]);
        return C;
    };

    auto SM = [&](f4 sc, f4 dv, int nt, int mg) {
        float p0 = exp2i(sc[0]), p1 = exp2i(sc[1]);
        float p2 = exp2i(sc[2]), p3 = exp2i(sc[3]);
        ps[nt] += (p0 + p1) + (p2 + p3);
        prop[nt] += p0 * dv[0] + p1 * dv[1] + p2 * dv[2] + p3 * dv[3];
        uint2 w;
        w.x = packbf2(p0, p1);
        w.y = packbf2(p2, p3);
        *(uint2*)(Pw + (size_t)(nt * 16 + nl) * PSTR + mg * 16 + g4 * 4) = w;
    };

    const int NC = Nn / 128;
    stage(0, 0);
    f4 dvc0 = *(const f4*)(dsb + wh * 32 + g4 * 4);
    f4 dvc1 = *(const f4*)(dsb + wh * 32 + 16 + g4 * 4);
    __syncthreads();   // compiler drains vmcnt(0) before s_barrier -> stage(0) landed

    for (int c = 0; c < NC; ++c) {
        int cur = c & 1;
        f4 dvn0 = (f4){0.f, 0.f, 0.f, 0.f}, dvn1 = dvn0;
        if (c + 1 < NC) {
            stage(cur ^ 1, c + 1);   // async DMA, in flight across this chunk's compute
            dvn0 = *(const f4*)(dsb + (c + 1) * 128 + wh * 32 + g4 * 4);
            dvn1 = *(const f4*)(dsb + (c + 1) * 128 + wh * 32 + 16 + g4 * 4);
        }
        const unsigned short* LK = &Sg[cur][0];
        const unsigned short* LV = &Sg[cur][4096];
        const unsigned short* LA = &Sg[cur][8192];

        // QK^T (swapped): S^T = mfma(K_frag, Q_frag, C=adj_frag)
        s8v kf0 = *(const s8v*)(LK + (((wh * 2 + 0) * 4 + g4) * 16 + nl) * 8);
        s8v kf1 = *(const s8v*)(LK + (((wh * 2 + 1) * 4 + g4) * 16 + nl) * 8);
        u16x4 a00 = *(const u16x4*)(LA + (wh * 8 + 0 + g4) * 64 + nl * 4);
        u16x4 a01 = *(const u16x4*)(LA + (wh * 8 + 4 + g4) * 64 + nl * 4);
        u16x4 a10 = *(const u16x4*)(LA + 2048 + (wh * 8 + 0 + g4) * 64 + nl * 4);
        u16x4 a11 = *(const u16x4*)(LA + 2048 + (wh * 8 + 4 + g4) * 64 + nl * 4);

        f4 sc00 = __builtin_amdgcn_mfma_f32_16x16x32_bf16(kf0, qf[0], mkC(a00), 0, 0, 0);
        f4 sc01 = __builtin_amdgcn_mfma_f32_16x16x32_bf16(kf1, qf[0], mkC(a01), 0, 0, 0);
        f4 sc10 = __builtin_amdgcn_mfma_f32_16x16x32_bf16(kf0, qf[1], mkC(a10), 0, 0, 0);
        f4 sc11 = __builtin_amdgcn_mfma_f32_16x16x32_bf16(kf1, qf[1], mkC(a11), 0, 0, 0);

        SM(sc00, dvc0, 0, 0);
        SM(sc01, dvc1, 0, 1);
        SM(sc10, dvc0, 1, 0);
        SM(sc11, dvc1, 1, 1);

        // PV: att^T[h][n] += V^T_frag * P^T_frag over this 32-m window
        s8v pb0 = *(const s8v*)(Pw + (size_t)(0 * 16 + nl) * PSTR + g4 * 8);
        s8v pb1 = *(const s8v*)(Pw + (size_t)(1 * 16 + nl) * PSTR + g4 * 8);
        s8v vf0 = *(const s8v*)(LV + ((wh * 4 + g4) * 32 + 0 * 16 + nl) * 8);
        s8v vf1 = *(const s8v*)(LV + ((wh * 4 + g4) * 32 + 1 * 16 + nl) * 8);
        pacc[0][0] = __builtin_amdgcn_mfma_f32_16x16x32_bf16(vf0, pb0, pacc[0][0], 0, 0, 0);
        pacc[0][1] = __builtin_amdgcn_mfma_f32_16x16x32_bf16(vf1, pb0, pacc[0][1], 0, 0, 0);
        pacc[1][0] = __builtin_amdgcn_mfma_f32_16x16x32_bf16(vf0, pb1, pacc[1][0], 0, 0, 0);
        pacc[1][1] = __builtin_amdgcn_mfma_f32_16x16x32_bf16(vf1, pb1, pacc[1][1], 0, 0, 0);

        __syncthreads();   // drains vmcnt(0): next buffer staged + all readers done
        dvc0 = dvn0; dvc1 = dvn1;
    }

    // cross-lane reduce of linear scalars (per n-col: sum over g4 groups)
    #pragma unroll
    for (int nt = 0; nt < 2; ++nt) {
        ps[nt] += __shfl_xor(ps[nt], 16);
        ps[nt] += __shfl_xor(ps[nt], 32);
        prop[nt] += __shfl_xor(prop[nt], 16);
        prop[nt] += __shfl_xor(prop[nt], 32);
    }

    // ---- linear merge across the 4 wh waves, scratch = Pt reinterpreted ----
    float* mrgb = (float*)&Pt[0][0];   // 2 regions x 64 lanes x 20 floats = 10240 B
    __syncthreads();                   // all PV reads of Pt done
    if (wh & 1) {                      // wh 1 -> region 0, wh 3 -> region 1
        float* d = mrgb + ((size_t)(wh >> 1) * 64 + lane) * 20;
        #pragma unroll
        for (int nt = 0; nt < 2; ++nt)
            #pragma unroll
            for (int t = 0; t < 2; ++t)
                #pragma unroll
                for (int r2 = 0; r2 < 4; ++r2) d[nt * 8 + t * 4 + r2] = pacc[nt][t][r2];
        d[16] = ps[0]; d[17] = ps[1]; d[18] = prop[0]; d[19] = prop[1];
    }
    __syncthreads();
    if (!(wh & 1)) {                   // wh 0 += region 0, wh 2 += region 1
        const float* d = mrgb + ((size_t)(wh >> 1) * 64 + lane) * 20;
        #pragma unroll
        for (int nt = 0; nt < 2; ++nt)
            #pragma unroll
            for (int t = 0; t < 2; ++t)
                #pragma unroll
                for (int r2 = 0; r2 < 4; ++r2) pacc[nt][t][r2] += d[nt * 8 + t * 4 + r2];
        ps[0] += d[16]; ps[1] += d[17]; prop[0] += d[18]; prop[1] += d[19];
    }
    __syncthreads();
    if (wh == 2) {
        float* d = mrgb + (size_t)lane * 20;
        #pragma unroll
        for (int nt = 0; nt < 2; ++nt)
            #pragma unroll
            for (int t = 0; t < 2; ++t)
                #pragma unroll
                for (int r2 = 0; r2 < 4; ++r2) d[nt * 8 + t * 4 + r2] = pacc[nt][t][r2];
        d[16] = ps[0]; d[17] = ps[1]; d[18] = prop[0]; d[19] = prop[1];
    }
    __syncthreads();
    if (wh == 0) {
        const float* d = mrgb + (size_t)lane * 20;
        #pragma unroll
        for (int nt = 0; nt < 2; ++nt)
            #pragma unroll
            for (int t = 0; t < 2; ++t)
                #pragma unroll
                for (int r2 = 0; r2 < 4; ++r2) pacc[nt][t][r2] += d[nt * 8 + t * 4 + r2];
        ps[0] += d[16]; ps[1] += d[17]; prop[0] += d[18]; prop[1] += d[19];

        // epilogue: comb(bf16) = feat + attended + 0.1*prop
        #pragma unroll
        for (int nt = 0; nt < 2; ++nt) {
            float invS = 1.f / ps[nt];
            float pp = prop[nt] * invS * 0.1f;
            size_t o = ((size_t)b * Nn + n0w + nt * 16 + nl) * Hh;
            #pragma unroll
            for (int t = 0; t < 2; ++t) {
                f4 fv = *(const f4*)(feat + o + t * 16 + g4 * 4);
                f4 ov = fv + pacc[nt][t] * invS;
                u16x4 cw;
                cw[0] = f2b(ov[0] + pp);
                cw[1] = f2b(ov[1] + pp);
                cw[2] = f2b(ov[2] + pp);
                cw[3] = f2b(ov[3] + pp);
                *(u16x4*)(comb + o + t * 16 + g4 * 4) = cw;
            }
        }
    }
}

// ---------------- output projection + LayerNorm (bf16 comb in) ----------------
__global__ void k_projln(const unsigned short* __restrict__ comb,
                         const float* __restrict__ Wo, const float* __restrict__ bo,
                         const float* __restrict__ gamma, const float* __restrict__ beta,
                         float* __restrict__ out) {
    __shared__ float WoT[Hh][Hh + 1];
    __shared__ float f[8][Hh];
    int tid = threadIdx.x;
    for (int i = tid; i < Hh * Hh; i += 256) {
        WoT[i & 31][i >> 5] = Wo[i];
    }
    int row0 = blockIdx.x * 8;
    f[tid >> 5][tid & 31] = b2f(comb[(size_t)row0 * Hh + tid]);
    __syncthreads();
    int lr = tid >> 5, h = tid & 31;
    float a = bo[h];
    #pragma unroll
    for (int k = 0; k < Hh; ++k) a += f[lr][k] * WoT[k][h];
    float mu = a;
    #pragma unroll
    for (int w = 1; w < 32; w <<= 1) mu += __shfl_xor(mu, w);
    mu *= (1.f / 32.f);
    float d = a - mu;
    float v = d * d;
    #pragma unroll
    for (int w = 1; w < 32; w <<= 1) v += __shfl_xor(v, w);
    v *= (1.f / 32.f);
    out[(size_t)row0 * Hh + tid] = d * rsqrtf(v + LN_EPS) * gamma[h] + beta[h];
}

extern "C" void kernel_launch(void* const* d_in, const int* in_sizes, int n_in,
                              void* d_out, int out_size, void* d_ws, size_t ws_size,
                              hipStream_t stream) {
    const float* x     = (const float*)d_in[0];
    const float* feat  = (const float*)d_in[1];
    const float* dlog  = (const float*)d_in[2];
    const float* Wq    = (const float*)d_in[3];
    const float* bq    = (const float*)d_in[4];
    const float* Wk    = (const float*)d_in[5];
    const float* bk    = (const float*)d_in[6];
    const float* Wv    = (const float*)d_in[7];
    const float* bv    = (const float*)d_in[8];
    const float* adj   = (const float*)d_in[9];
    const float* geo   = (const float*)d_in[10];
    const float* Wo    = (const float*)d_in[11];
    const float* bo    = (const float*)d_in[12];
    const float* gamma = (const float*)d_in[13];
    const float* beta  = (const float*)d_in[14];
    float* out = (float*)d_out;

    char* w = (char*)d_ws;
    unsigned short* Qbf  = (unsigned short*)w;  w += (size_t)Bb * Nn * Hh * 2;
    unsigned short* Kf   = (unsigned short*)w;  w += (size_t)Bb * Nn * Hh * 2;
    unsigned short* Vf   = (unsigned short*)w;  w += (size_t)Bb * Nn * Hh * 2;
    unsigned short* adjF = (unsigned short*)w;  w += (size_t)Nn * Nn * 2;
    float* dsg           = (float*)w;           w += (size_t)Bb * Nn * 4;
    unsigned short* comb = (unsigned short*)w;

    k_adjprep<<<512, 256, 0, stream>>>(adj, geo, adjF);
    k_delayed<<<(Bb * Nn + 255) / 256, 256, 0, stream>>>(x, dlog, dsg);
    k_qkv<<<Bb * Nn / 8, 256, 0, stream>>>(feat, Wq, bq, Wk, bk, Wv, bv, geo, Qbf, Kf, Vf);
    k_attn<<<1024, 256, 0, stream>>>(Qbf, Kf, Vf, adjF, dsg, feat, comb);
    k_projln<<<Bb * Nn / 8, 256, 0, stream>>>(comb, Wo, bo, gamma, beta, out);
}

// Round 15
// 59.921 us; speedup vs baseline: 1.2794x; 1.2794x over previous
//
#include <hip/hip_runtime.h>
#include <hip/hip_bf16.h>
#include <math.h>
#include <stdint.h>

#define Bb 16
#define Tt 28
#define Nn 2048
#define Hh 32
#define LAGS 8
#define LN_EPS 1e-5f
#define PSTR 56                      // P row stride (shorts): 2-way banks on b128/b64
#define LOG2E 1.4426950408889634f

typedef float f4 __attribute__((ext_vector_type(4)));
typedef short s8v __attribute__((ext_vector_type(8)));
typedef unsigned short u16x4 __attribute__((ext_vector_type(4)));
typedef unsigned short u16x8 __attribute__((ext_vector_type(8)));

__device__ __forceinline__ float b2f(unsigned short u) {
    union { unsigned uu; float ff; } x; x.uu = ((unsigned)u) << 16; return x.ff;
}
__device__ __forceinline__ unsigned short f2b(float f) {
    unsigned u = __float_as_uint(f);
    u += 0x7FFFu + ((u >> 16) & 1u);   // RNE
    return (unsigned short)(u >> 16);
}
__device__ __forceinline__ unsigned packbf2(float lo, float hi) {
    __hip_bfloat162 h = __float22bfloat162_rn(make_float2(lo, hi));
    union { __hip_bfloat162 h2; unsigned u; } c; c.h2 = h; return c.u;
}
__device__ __forceinline__ float exp2i(float x) {   // native 2^x, single instr
    float r; asm("v_exp_f32 %0, %1" : "=v"(r) : "v"(x)); return r;
}

// ---------- adj fp32 -> bf16 scaled by geo*5*log2e, fragment-tile layout ----------
// adjF[((n>>4)*512 + (m>>2))*64 + (n&15)*4 + (m&3)]
__global__ void k_adjprep(const float* __restrict__ adj, const float* __restrict__ geo_w,
                          unsigned short* __restrict__ adjF) {
    __shared__ float T[16][516];
    float geo = 1.f / (1.f + __expf(-geo_w[0]));
    float cg = geo * 5.f * LOG2E;
    int tid = threadIdx.x;
    int g = blockIdx.x >> 2, q = blockIdx.x & 3;
    int n0 = g * 16, m0 = q * 512;
    #pragma unroll
    for (int r = 0; r < 16; ++r) {
        T[r][tid] = adj[(size_t)(n0 + r) * Nn + m0 + tid];
        T[r][tid + 256] = adj[(size_t)(n0 + r) * Nn + m0 + tid + 256];
    }
    __syncthreads();
    unsigned short* region = adjF + ((size_t)g * 512 + q * 128) * 64;
    #pragma unroll
    for (int i = 0; i < 4; ++i) {
        int e0 = (i * 256 + tid) * 8;
        u16x8 w;
        #pragma unroll
        for (int j = 0; j < 8; ++j) {
            int e = e0 + j;
            int mq = e >> 6, nl = (e >> 2) & 15, mm = e & 3;
            w[j] = f2b(cg * T[nl][mq * 4 + mm]);
        }
        *(u16x8*)(region + e0) = w;
    }
}

// ---------- fused QKV + delayed-signal: Q prescaled; K frag; V 48-row frag ----------
// Kf[((b*128+(m>>4))*4+(k>>3))*16+(m&15)][8]        -> 65536 shorts/batch
// Vf[((b*64+(m>>5))*4+((m>>3)&3))*48 + h][8], h<48  -> 98304 shorts/batch
//   rows 0..31 = V^T, row 32 = delayed signal, row 33 = 1.0, rows 34..47 = 0
__global__ void k_qkv(const float* __restrict__ feat, const float* __restrict__ x,
                      const float* __restrict__ dlog,
                      const float* __restrict__ Wq, const float* __restrict__ bq,
                      const float* __restrict__ Wk, const float* __restrict__ bk,
                      const float* __restrict__ Wv, const float* __restrict__ bv,
                      const float* __restrict__ geo_w,
                      unsigned short* __restrict__ Qbf, unsigned short* __restrict__ Kf,
                      unsigned short* __restrict__ Vf) {
    __shared__ float WqT[Hh][Hh + 1], WkT[Hh][Hh + 1], WvT[Hh][Hh + 1];
    __shared__ float f[8][Hh];
    __shared__ __align__(16) unsigned short VT8[Hh][8];
    __shared__ __align__(16) unsigned short DS8[8];
    int tid = threadIdx.x;
    for (int i = tid; i < Hh * Hh; i += 256) {
        int h = i >> 5, k = i & 31;
        WqT[k][h] = Wq[i];
        WkT[k][h] = Wk[i];
        WvT[k][h] = Wv[i];
    }
    int n0 = blockIdx.x * 8;
    int b = n0 >> 11, mloc0 = n0 & 2047;
    // ---- delayed signal for this 8-row octet (wave 0 only) ----
    if (tid < 64) {
        float mx = -1e30f;
        #pragma unroll
        for (int t = 0; t < LAGS; ++t) mx = fmaxf(mx, dlog[t]);
        float s = 0.f, wv[LAGS];
        #pragma unroll
        for (int t = 0; t < LAGS; ++t) { wv[t] = __expf(dlog[t] - mx); s += wv[t]; }
        int t = tid >> 3, j = tid & 7;
        float dsv = (wv[t] / s) * x[(size_t)b * Tt * Nn + (size_t)(Tt - 1 - t) * Nn + mloc0 + j];
        dsv += __shfl_xor(dsv, 8);
        dsv += __shfl_xor(dsv, 16);
        dsv += __shfl_xor(dsv, 32);
        if (tid < 8) DS8[tid] = f2b(dsv);
    }
    float geo = 1.f / (1.f + __expf(-geo_w[0]));
    float csL = (1.f - geo) * 0.17677669529663687f * LOG2E;
    f[tid >> 5][tid & 31] = feat[(size_t)n0 * Hh + tid];
    __syncthreads();
    int lr = tid >> 5, h = tid & 31;
    float aq = bq[h], ak = bk[h], av = bv[h];
    #pragma unroll
    for (int k = 0; k < Hh; ++k) {
        float fv = f[lr][k];
        aq += fv * WqT[k][h];
        ak += fv * WkT[k][h];
        av += fv * WvT[k][h];
    }
    Qbf[(size_t)(n0 + lr) * Hh + h] = f2b(aq * csL);
    int mloc = mloc0 + lr;
    size_t kaddr = ((((size_t)b * 128 + (mloc >> 4)) * 4 + (h >> 3)) * 16 + (mloc & 15)) * 8 + (h & 7);
    Kf[kaddr] = f2b(ak);
    VT8[h][lr] = f2b(av);
    __syncthreads();
    size_t vbase = (((size_t)b * 64 + (mloc0 >> 5)) * 4 + ((mloc0 >> 3) & 3)) * 48;
    if (tid < 32) {
        *(u16x8*)(Vf + (vbase + tid) * 8) = *(const u16x8*)&VT8[tid][0];
    } else if (tid < 48) {
        int rr = tid - 32;            // 0=ds, 1=ones, 2..15=zero
        u16x8 wv8;
        if (rr == 0) {
            wv8 = *(const u16x8*)&DS8[0];
        } else {
            unsigned short fill = (rr == 1) ? (unsigned short)0x3F80 : (unsigned short)0;
            for (int j = 0; j < 8; ++j) wv8[j] = fill;
        }
        *(u16x8*)(Vf + (vbase + 32 + rr) * 8) = wv8;
    }
}

// ---------------- MFMA attention + fused output-proj + LayerNorm ------------------
// 4 waves/block, 32 n-cols, wave wh owns 32-m quarter of each 128-chunk.
// Direct-from-L2 fragment loads, barrier-free main loop (r11 structure).
// prop & ps come out of PV MFMA tile t=2 (V rows 32=ds, 33=ones).
__global__ __launch_bounds__(256)
void k_attn(const unsigned short* __restrict__ Qbf,
            const unsigned short* __restrict__ Kf,
            const unsigned short* __restrict__ Vf,
            const unsigned short* __restrict__ adjF,
            const float* __restrict__ feat,
            const float* __restrict__ Wo, const float* __restrict__ bo,
            const float* __restrict__ gamma, const float* __restrict__ beta,
            float* __restrict__ out) {
    __shared__ __align__(16) unsigned short Pt[4][32 * PSTR];   // 14336 B; merge scratch later
    __shared__ float WoT[Hh][Hh + 1];
    __shared__ float combT[32][Hh + 1];
    __shared__ float gbb[3][Hh];

    int tid = threadIdx.x;
    int wid = tid >> 6, lane = tid & 63;
    int nl = lane & 15, g4 = lane >> 4;
    int wh = wid;

    for (int i = tid; i < Hh * Hh; i += 256) WoT[i & 31][i >> 5] = Wo[i];
    if (tid < 32) { gbb[0][tid] = bo[tid]; gbb[1][tid] = gamma[tid]; gbb[2][tid] = beta[tid]; }

    // XCD-partitioned swizzle: xcd = bid&7 -> (n-quarter = xcd>>1, batch-half = xcd&1)
    int bid = blockIdx.x;
    int xcd = bid & 7, r = bid >> 3;            // r: 0..127
    int b = ((xcd & 1) << 3) + (r & 7);
    int nt32 = ((xcd >> 1) << 4) + (r >> 3);    // 0..63
    int n0w = nt32 * 32;

    // Q B-fragments (col = n = nl, k = g4*8+j); Q pre-scaled by cs*log2e
    s8v qf[2];
    #pragma unroll
    for (int nt = 0; nt < 2; ++nt)
        qf[nt] = *(const s8v*)(Qbf + (((size_t)b * Nn + n0w + nt * 16 + nl) << 5) + g4 * 8);

    f4 pacc[2][3];
    #pragma unroll
    for (int nt = 0; nt < 2; ++nt)
        #pragma unroll
        for (int t = 0; t < 3; ++t) pacc[nt][t] = (f4){0.f, 0.f, 0.f, 0.f};

    const unsigned short* Kb = Kf + (size_t)b * 65536;
    const unsigned short* Vb = Vf + (size_t)b * 98304;
    unsigned short* Pw = Pt[wid];

    struct Frag {
        s8v kf0, kf1, vf0, vf1, vf2;
        u16x4 a00, a01, a10, a11;
    };

    auto load = [&](Frag& F, int c) {
        int mw = c * 128 + wh * 32;
        F.kf0 = *(const s8v*)(Kb + ((((size_t)(mw >> 4) + 0) * 4 + g4) * 16 + nl) * 8);
        F.kf1 = *(const s8v*)(Kb + ((((size_t)(mw >> 4) + 1) * 4 + g4) * 16 + nl) * 8);
        F.vf0 = *(const s8v*)(Vb + (((size_t)(mw >> 5) * 4 + g4) * 48 + 0 * 16 + nl) * 8);
        F.vf1 = *(const s8v*)(Vb + (((size_t)(mw >> 5) * 4 + g4) * 48 + 1 * 16 + nl) * 8);
        F.vf2 = *(const s8v*)(Vb + (((size_t)(mw >> 5) * 4 + g4) * 48 + 2 * 16 + nl) * 8);
        size_t arow0 = (size_t)((n0w >> 4) + 0) * 512 + (mw >> 2);
        size_t arow1 = (size_t)((n0w >> 4) + 1) * 512 + (mw >> 2);
        F.a00 = *(const u16x4*)(adjF + (arow0 + 0 + g4) * 64 + nl * 4);
        F.a01 = *(const u16x4*)(adjF + (arow0 + 4 + g4) * 64 + nl * 4);
        F.a10 = *(const u16x4*)(adjF + (arow1 + 0 + g4) * 64 + nl * 4);
        F.a11 = *(const u16x4*)(adjF + (arow1 + 4 + g4) * 64 + nl * 4);
    };

    auto mkC = [&](u16x4 av) -> f4 {
        f4 C;
        C[0] = b2f(av[0]); C[1] = b2f(av[1]); C[2] = b2f(av[2]); C[3] = b2f(av[3]);
        return C;
    };

    auto SM = [&](f4 sc, int nt, int mg) {
        float p0 = exp2i(sc[0]), p1 = exp2i(sc[1]);
        float p2 = exp2i(sc[2]), p3 = exp2i(sc[3]);
        uint2 w;
        w.x = packbf2(p0, p1);
        w.y = packbf2(p2, p3);
        *(uint2*)(Pw + (size_t)(nt * 16 + nl) * PSTR + mg * 16 + g4 * 4) = w;
    };

    auto compute = [&](Frag& F) {
        f4 sc00 = __builtin_amdgcn_mfma_f32_16x16x32_bf16(F.kf0, qf[0], mkC(F.a00), 0, 0, 0);
        f4 sc01 = __builtin_amdgcn_mfma_f32_16x16x32_bf16(F.kf1, qf[0], mkC(F.a01), 0, 0, 0);
        f4 sc10 = __builtin_amdgcn_mfma_f32_16x16x32_bf16(F.kf0, qf[1], mkC(F.a10), 0, 0, 0);
        f4 sc11 = __builtin_amdgcn_mfma_f32_16x16x32_bf16(F.kf1, qf[1], mkC(F.a11), 0, 0, 0);
        SM(sc00, 0, 0);
        SM(sc01, 0, 1);
        SM(sc10, 1, 0);
        SM(sc11, 1, 1);
        s8v pb0 = *(const s8v*)(Pw + (size_t)(0 * 16 + nl) * PSTR + g4 * 8);
        s8v pb1 = *(const s8v*)(Pw + (size_t)(1 * 16 + nl) * PSTR + g4 * 8);
        pacc[0][0] = __builtin_amdgcn_mfma_f32_16x16x32_bf16(F.vf0, pb0, pacc[0][0], 0, 0, 0);
        pacc[0][1] = __builtin_amdgcn_mfma_f32_16x16x32_bf16(F.vf1, pb0, pacc[0][1], 0, 0, 0);
        pacc[0][2] = __builtin_amdgcn_mfma_f32_16x16x32_bf16(F.vf2, pb0, pacc[0][2], 0, 0, 0);
        pacc[1][0] = __builtin_amdgcn_mfma_f32_16x16x32_bf16(F.vf0, pb1, pacc[1][0], 0, 0, 0);
        pacc[1][1] = __builtin_amdgcn_mfma_f32_16x16x32_bf16(F.vf1, pb1, pacc[1][1], 0, 0, 0);
        pacc[1][2] = __builtin_amdgcn_mfma_f32_16x16x32_bf16(F.vf2, pb1, pacc[1][2], 0, 0, 0);
    };

    const int NC = Nn / 128;
    Frag A, B;
    load(A, 0);
    for (int c = 0; c < NC; c += 2) {
        load(B, c + 1);                    // prefetch while computing A
        compute(A);
        if (c + 2 < NC) load(A, c + 2);    // prefetch while computing B
        compute(B);
    }

    // ---- linear merge of pacc (24 floats/lane) across the 4 wh waves ----
    float* mrgb = (float*)&Pt[0][0];   // 2 regions x 64 lanes x 24 floats = 12288 B <= 14336
    __syncthreads();                   // all PV reads of Pt done
    if (wh & 1) {
        float* d = mrgb + ((size_t)(wh >> 1) * 64 + lane) * 24;
        #pragma unroll
        for (int nt = 0; nt < 2; ++nt)
            #pragma unroll
            for (int t = 0; t < 3; ++t)
                #pragma unroll
                for (int r2 = 0; r2 < 4; ++r2) d[(nt * 3 + t) * 4 + r2] = pacc[nt][t][r2];
    }
    __syncthreads();
    if (!(wh & 1)) {
        const float* d = mrgb + ((size_t)(wh >> 1) * 64 + lane) * 24;
        #pragma unroll
        for (int nt = 0; nt < 2; ++nt)
            #pragma unroll
            for (int t = 0; t < 3; ++t)
                #pragma unroll
                for (int r2 = 0; r2 < 4; ++r2) pacc[nt][t][r2] += d[(nt * 3 + t) * 4 + r2];
    }
    __syncthreads();
    if (wh == 2) {
        float* d = mrgb + (size_t)lane * 24;
        #pragma unroll
        for (int nt = 0; nt < 2; ++nt)
            #pragma unroll
            for (int t = 0; t < 3; ++t)
                #pragma unroll
                for (int r2 = 0; r2 < 4; ++r2) d[(nt * 3 + t) * 4 + r2] = pacc[nt][t][r2];
    }
    __syncthreads();
    if (wh == 0) {
        const float* d = mrgb + (size_t)lane * 24;
        #pragma unroll
        for (int nt = 0; nt < 2; ++nt)
            #pragma unroll
            for (int t = 0; t < 3; ++t)
                #pragma unroll
                for (int r2 = 0; r2 < 4; ++r2) pacc[nt][t][r2] += d[(nt * 3 + t) * 4 + r2];

        // comb = feat + attended/ps + 0.1*prop/ps  -> combT (LDS)
        #pragma unroll
        for (int nt = 0; nt < 2; ++nt) {
            float psn = __shfl(pacc[nt][2][1], nl);   // ones-row (h=33): g4==0, reg 1
            float prn = __shfl(pacc[nt][2][0], nl);   // ds-row   (h=32): g4==0, reg 0
            float invS = 1.f / psn;
            float pp = prn * invS * 0.1f;
            size_t o = ((size_t)b * Nn + n0w + nt * 16 + nl) * Hh;
            #pragma unroll
            for (int t = 0; t < 2; ++t) {
                f4 fv = *(const f4*)(feat + o + t * 16 + g4 * 4);
                #pragma unroll
                for (int r2 = 0; r2 < 4; ++r2)
                    combT[nt * 16 + nl][t * 16 + g4 * 4 + r2] = fv[r2] + pacc[nt][t][r2] * invS + pp;
            }
        }
    }
    __syncthreads();

    // ---- fused output projection + LayerNorm (each wave: 8 rows) ----
    int h = lane & 31;
    #pragma unroll
    for (int pass = 0; pass < 4; ++pass) {
        int row = wh * 8 + pass * 2 + (lane >> 5);
        float a = gbb[0][h];
        #pragma unroll
        for (int k = 0; k < Hh; ++k) a += combT[row][k] * WoT[k][h];
        float mu = a;
        #pragma unroll
        for (int w = 1; w < 32; w <<= 1) mu += __shfl_xor(mu, w);
        mu *= (1.f / 32.f);
        float dd = a - mu;
        float v = dd * dd;
        #pragma unroll
        for (int w = 1; w < 32; w <<= 1) v += __shfl_xor(v, w);
        v *= (1.f / 32.f);
        out[((size_t)b * Nn + n0w + row) * Hh + h] =
            dd * rsqrtf(v + LN_EPS) * gbb[1][h] + gbb[2][h];
    }
}

extern "C" void kernel_launch(void* const* d_in, const int* in_sizes, int n_in,
                              void* d_out, int out_size, void* d_ws, size_t ws_size,
                              hipStream_t stream) {
    const float* x     = (const float*)d_in[0];
    const float* feat  = (const float*)d_in[1];
    const float* dlog  = (const float*)d_in[2];
    const float* Wq    = (const float*)d_in[3];
    const float* bq    = (const float*)d_in[4];
    const float* Wk    = (const float*)d_in[5];
    const float* bk    = (const float*)d_in[6];
    const float* Wv    = (const float*)d_in[7];
    const float* bv    = (const float*)d_in[8];
    const float* adj   = (const float*)d_in[9];
    const float* geo   = (const float*)d_in[10];
    const float* Wo    = (const float*)d_in[11];
    const float* bo    = (const float*)d_in[12];
    const float* gamma = (const float*)d_in[13];
    const float* beta  = (const float*)d_in[14];
    float* out = (float*)d_out;

    char* w = (char*)d_ws;
    unsigned short* Qbf  = (unsigned short*)w;  w += (size_t)Bb * Nn * Hh * 2;
    unsigned short* Kf   = (unsigned short*)w;  w += (size_t)Bb * Nn * Hh * 2;
    unsigned short* Vf   = (unsigned short*)w;  w += (size_t)Bb * 98304 * 2;   // 48-row frag
    unsigned short* adjF = (unsigned short*)w;  w += (size_t)Nn * Nn * 2;

    k_adjprep<<<512, 256, 0, stream>>>(adj, geo, adjF);
    k_qkv<<<Bb * Nn / 8, 256, 0, stream>>>(feat, x, dlog, Wq, bq, Wk, bk, Wv, bv, geo,
                                           Qbf, Kf, Vf);
    k_attn<<<1024, 256, 0, stream>>>(Qbf, Kf, Vf, adjF, feat, Wo, bo, gamma, beta, out);
}

// Round 17
// 53.964 us; speedup vs baseline: 1.4207x; 1.1104x over previous
//
#include <hip/hip_runtime.h>
#include <hip/hip_bf16.h>
#include <math.h>
#include <stdint.h>

#define Bb 16
#define Tt 28
#define Nn 2048
#define Hh 32
#define LAGS 8
#define LN_EPS 1e-5f
#define PSTR 56                      // P row stride (shorts): 2-way banks on b128/b64

typedef float f4 __attribute__((ext_vector_type(4)));
typedef short s8v __attribute__((ext_vector_type(8)));
typedef unsigned short u16x4 __attribute__((ext_vector_type(4)));
typedef unsigned short u16x8 __attribute__((ext_vector_type(8)));

__device__ __forceinline__ float b2f(unsigned short u) {
    union { unsigned uu; float ff; } x; x.uu = ((unsigned)u) << 16; return x.ff;
}
__device__ __forceinline__ unsigned short f2b(float f) {
    unsigned u = __float_as_uint(f);
    u += 0x7FFFu + ((u >> 16) & 1u);   // RNE
    return (unsigned short)(u >> 16);
}
__device__ __forceinline__ unsigned packbf2(float lo, float hi) {
    __hip_bfloat162 h = __float22bfloat162_rn(make_float2(lo, hi));
    union { __hip_bfloat162 h2; unsigned u; } c; c.h2 = h; return c.u;
}

// ---------- adj fp32 -> bf16 scaled by geo*5, fragment-tile layout ----------
// adjF[((n>>4)*512 + (m>>2))*64 + (n&15)*4 + (m&3)]
__global__ void k_adjprep(const float* __restrict__ adj, const float* __restrict__ geo_w,
                          unsigned short* __restrict__ adjF) {
    __shared__ float T[16][516];
    float geo = 1.f / (1.f + __expf(-geo_w[0]));
    float cg = geo * 5.f;
    int tid = threadIdx.x;
    int g = blockIdx.x >> 2, q = blockIdx.x & 3;
    int n0 = g * 16, m0 = q * 512;
    #pragma unroll
    for (int r = 0; r < 16; ++r) {
        T[r][tid] = adj[(size_t)(n0 + r) * Nn + m0 + tid];
        T[r][tid + 256] = adj[(size_t)(n0 + r) * Nn + m0 + tid + 256];
    }
    __syncthreads();
    unsigned short* region = adjF + ((size_t)g * 512 + q * 128) * 64;
    #pragma unroll
    for (int i = 0; i < 4; ++i) {
        int e0 = (i * 256 + tid) * 8;
        u16x8 w;
        #pragma unroll
        for (int j = 0; j < 8; ++j) {
            int e = e0 + j;
            int mq = e >> 6, nl = (e >> 2) & 15, mm = e & 3;
            w[j] = f2b(cg * T[nl][mq * 4 + mm]);
        }
        *(u16x8*)(region + e0) = w;
    }
}

// ---------- fused QKV + delayed-signal: Q prescaled by cs; K frag; V 48-row frag ----
// Kf[((b*128+(m>>4))*4+(k>>3))*16+(m&15)][8]        -> 65536 shorts/batch
// Vf[((b*64+(m>>5))*4+((m>>3)&3))*48 + h][8], h<48  -> 98304 shorts/batch
//   rows 0..31 = V^T, row 32 = delayed signal, row 33 = 1.0, rows 34..47 = 0
__global__ void k_qkv(const float* __restrict__ feat, const float* __restrict__ x,
                      const float* __restrict__ dlog,
                      const float* __restrict__ Wq, const float* __restrict__ bq,
                      const float* __restrict__ Wk, const float* __restrict__ bk,
                      const float* __restrict__ Wv, const float* __restrict__ bv,
                      const float* __restrict__ geo_w,
                      unsigned short* __restrict__ Qbf, unsigned short* __restrict__ Kf,
                      unsigned short* __restrict__ Vf) {
    __shared__ float WqT[Hh][Hh + 1], WkT[Hh][Hh + 1], WvT[Hh][Hh + 1];
    __shared__ float f[8][Hh];
    __shared__ __align__(16) unsigned short VT8[Hh][8];
    __shared__ __align__(16) unsigned short DS8[8];
    int tid = threadIdx.x;
    for (int i = tid; i < Hh * Hh; i += 256) {
        int h = i >> 5, k = i & 31;
        WqT[k][h] = Wq[i];
        WkT[k][h] = Wk[i];
        WvT[k][h] = Wv[i];
    }
    int n0 = blockIdx.x * 8;
    int b = n0 >> 11, mloc0 = n0 & 2047;
    // ---- delayed signal for this 8-row octet (wave 0 only) ----
    if (tid < 64) {
        float mx = -1e30f;
        #pragma unroll
        for (int t = 0; t < LAGS; ++t) mx = fmaxf(mx, dlog[t]);
        float s = 0.f, wv[LAGS];
        #pragma unroll
        for (int t = 0; t < LAGS; ++t) { wv[t] = __expf(dlog[t] - mx); s += wv[t]; }
        int t = tid >> 3, j = tid & 7;
        float dsv = (wv[t] / s) * x[(size_t)b * Tt * Nn + (size_t)(Tt - 1 - t) * Nn + mloc0 + j];
        dsv += __shfl_xor(dsv, 8);
        dsv += __shfl_xor(dsv, 16);
        dsv += __shfl_xor(dsv, 32);
        if (tid < 8) DS8[tid] = f2b(dsv);
    }
    float geo = 1.f / (1.f + __expf(-geo_w[0]));
    float cs = (1.f - geo) * 0.17677669529663687f;   // (1-geo)/sqrt(32)
    f[tid >> 5][tid & 31] = feat[(size_t)n0 * Hh + tid];
    __syncthreads();
    int lr = tid >> 5, h = tid & 31;
    float aq = bq[h], ak = bk[h], av = bv[h];
    #pragma unroll
    for (int k = 0; k < Hh; ++k) {
        float fv = f[lr][k];
        aq += fv * WqT[k][h];
        ak += fv * WkT[k][h];
        av += fv * WvT[k][h];
    }
    Qbf[(size_t)(n0 + lr) * Hh + h] = f2b(aq * cs);
    int mloc = mloc0 + lr;
    size_t kaddr = ((((size_t)b * 128 + (mloc >> 4)) * 4 + (h >> 3)) * 16 + (mloc & 15)) * 8 + (h & 7);
    Kf[kaddr] = f2b(ak);
    VT8[h][lr] = f2b(av);
    __syncthreads();
    size_t vbase = (((size_t)b * 64 + (mloc0 >> 5)) * 4 + ((mloc0 >> 3) & 3)) * 48;
    if (tid < 32) {
        *(u16x8*)(Vf + (vbase + tid) * 8) = *(const u16x8*)&VT8[tid][0];
    } else if (tid < 48) {
        int rr = tid - 32;            // 0=ds, 1=ones, 2..15=zero
        u16x8 wv8;
        if (rr == 0) {
            wv8 = *(const u16x8*)&DS8[0];
        } else {
            unsigned short fill = (rr == 1) ? (unsigned short)0x3F80 : (unsigned short)0;
            for (int j = 0; j < 8; ++j) wv8[j] = fill;
        }
        *(u16x8*)(Vf + (vbase + 32 + rr) * 8) = wv8;
    }
}

// ---------------- MFMA attention + fused output-proj + LayerNorm ------------------
// 4 waves/block, 32 n-cols, wave wh owns 32-m quarter of each 128-chunk.
// Pointer-bump direct-from-L2 loads; (256,2) keeps both ping-pong Frags live.
// exp via __expf (compiler-known v_exp_f32 with proper hazard handling — r16's
// bare inline-asm v_exp_f32 is the prime suspect for the 0.23 absmax failure).
__global__ __launch_bounds__(256, 2)
void k_attn(const unsigned short* __restrict__ Qbf,
            const unsigned short* __restrict__ Kf,
            const unsigned short* __restrict__ Vf,
            const unsigned short* __restrict__ adjF,
            const float* __restrict__ feat,
            const float* __restrict__ Wo, const float* __restrict__ bo,
            const float* __restrict__ gamma, const float* __restrict__ beta,
            float* __restrict__ out) {
    __shared__ __align__(16) unsigned short Pt[4][32 * PSTR];   // 14336 B; merge scratch later
    __shared__ float WoT[Hh][Hh + 1];
    __shared__ float combT[32][Hh + 1];
    __shared__ float gbb[3][Hh];

    int tid = threadIdx.x;
    int wid = tid >> 6, lane = tid & 63;
    int nl = lane & 15, g4 = lane >> 4;
    int wh = wid;

    for (int i = tid; i < Hh * Hh; i += 256) WoT[i & 31][i >> 5] = Wo[i];
    if (tid < 32) { gbb[0][tid] = bo[tid]; gbb[1][tid] = gamma[tid]; gbb[2][tid] = beta[tid]; }

    // XCD-partitioned swizzle: xcd = bid&7 -> (n-quarter = xcd>>1, batch-half = xcd&1)
    int bid = blockIdx.x;
    int xcd = bid & 7, r = bid >> 3;            // r: 0..127
    int b = ((xcd & 1) << 3) + (r & 7);
    int nt32 = ((xcd >> 1) << 4) + (r >> 3);    // 0..63
    int n0w = nt32 * 32;

    // Q B-fragments (col = n = nl, k = g4*8+j); Q pre-scaled by cs
    s8v qf[2];
    #pragma unroll
    for (int nt = 0; nt < 2; ++nt)
        qf[nt] = *(const s8v*)(Qbf + (((size_t)b * Nn + n0w + nt * 16 + nl) << 5) + g4 * 8);

    f4 pacc[2][3];
    #pragma unroll
    for (int nt = 0; nt < 2; ++nt)
        #pragma unroll
        for (int t = 0; t < 3; ++t) pacc[nt][t] = (f4){0.f, 0.f, 0.f, 0.f};

    const unsigned short* Kb = Kf + (size_t)b * 65536;
    const unsigned short* Vb = Vf + (size_t)b * 98304;
    unsigned short* Pw = Pt[wid];

    // pointer-bump bases (chunk 0, this wave's 32-m window)
    const unsigned short* pK  = Kb + (((size_t)(wh * 2) * 4 + g4) * 16 + nl) * 8;
    const unsigned short* pV  = Vb + (((size_t)wh * 4 + g4) * 48 + nl) * 8;
    const unsigned short* pA0 = adjF + ((size_t)(nt32 * 2) * 512 + wh * 8 + g4) * 64 + nl * 4;
    const unsigned short* pA1 = adjF + ((size_t)(nt32 * 2 + 1) * 512 + wh * 8 + g4) * 64 + nl * 4;

    struct Frag {
        s8v kf0, kf1, vf0, vf1, vf2;
        u16x4 a00, a01, a10, a11;
    };

    // load current chunk via running pointers (+imm offsets), then bump by chunk stride
    auto loadP = [&](Frag& F) {
        F.kf0 = *(const s8v*)(pK);
        F.kf1 = *(const s8v*)(pK + 512);     // +1 k-tile   (1024 B imm)
        F.vf0 = *(const s8v*)(pV);
        F.vf1 = *(const s8v*)(pV + 128);     // +16 rows    (256 B imm)
        F.vf2 = *(const s8v*)(pV + 256);     // +32 rows    (512 B imm)
        F.a00 = *(const u16x4*)(pA0);
        F.a01 = *(const u16x4*)(pA0 + 256);  // +4 m-quads  (512 B imm)
        F.a10 = *(const u16x4*)(pA1);
        F.a11 = *(const u16x4*)(pA1 + 256);
        pK += 4096;                          // +128 m
        pV += 6144;
        pA0 += 2048;
        pA1 += 2048;
    };

    auto mkC = [&](u16x4 av) -> f4 {
        f4 C;
        C[0] = b2f(av[0]); C[1] = b2f(av[1]); C[2] = b2f(av[2]); C[3] = b2f(av[3]);
        return C;
    };

    auto SM = [&](f4 sc, int nt, int mg) {
        float p0 = __expf(sc[0]), p1 = __expf(sc[1]);
        float p2 = __expf(sc[2]), p3 = __expf(sc[3]);
        uint2 w;
        w.x = packbf2(p0, p1);
        w.y = packbf2(p2, p3);
        *(uint2*)(Pw + (size_t)(nt * 16 + nl) * PSTR + mg * 16 + g4 * 4) = w;
    };

    auto compute = [&](Frag& F) {
        f4 sc00 = __builtin_amdgcn_mfma_f32_16x16x32_bf16(F.kf0, qf[0], mkC(F.a00), 0, 0, 0);
        f4 sc01 = __builtin_amdgcn_mfma_f32_16x16x32_bf16(F.kf1, qf[0], mkC(F.a01), 0, 0, 0);
        f4 sc10 = __builtin_amdgcn_mfma_f32_16x16x32_bf16(F.kf0, qf[1], mkC(F.a10), 0, 0, 0);
        f4 sc11 = __builtin_amdgcn_mfma_f32_16x16x32_bf16(F.kf1, qf[1], mkC(F.a11), 0, 0, 0);
        SM(sc00, 0, 0);
        SM(sc01, 0, 1);
        SM(sc10, 1, 0);
        SM(sc11, 1, 1);
        s8v pb0 = *(const s8v*)(Pw + (size_t)(0 * 16 + nl) * PSTR + g4 * 8);
        s8v pb1 = *(const s8v*)(Pw + (size_t)(1 * 16 + nl) * PSTR + g4 * 8);
        pacc[0][0] = __builtin_amdgcn_mfma_f32_16x16x32_bf16(F.vf0, pb0, pacc[0][0], 0, 0, 0);
        pacc[0][1] = __builtin_amdgcn_mfma_f32_16x16x32_bf16(F.vf1, pb0, pacc[0][1], 0, 0, 0);
        pacc[0][2] = __builtin_amdgcn_mfma_f32_16x16x32_bf16(F.vf2, pb0, pacc[0][2], 0, 0, 0);
        pacc[1][0] = __builtin_amdgcn_mfma_f32_16x16x32_bf16(F.vf0, pb1, pacc[1][0], 0, 0, 0);
        pacc[1][1] = __builtin_amdgcn_mfma_f32_16x16x32_bf16(F.vf1, pb1, pacc[1][1], 0, 0, 0);
        pacc[1][2] = __builtin_amdgcn_mfma_f32_16x16x32_bf16(F.vf2, pb1, pacc[1][2], 0, 0, 0);
    };

    const int NC = Nn / 128;
    Frag A, B;
    loadP(A);
    for (int c = 0; c < NC; c += 2) {
        loadP(B);                          // prefetch chunk c+1 while computing A
        compute(A);
        if (c + 2 < NC) loadP(A);          // prefetch chunk c+2 while computing B
        compute(B);
    }

    // ---- linear merge of pacc (24 floats/lane) across the 4 wh waves ----
    float* mrgb = (float*)&Pt[0][0];   // 2 regions x 64 lanes x 24 floats = 12288 B <= 14336
    __syncthreads();                   // all PV reads of Pt done
    if (wh & 1) {
        float* d = mrgb + ((size_t)(wh >> 1) * 64 + lane) * 24;
        #pragma unroll
        for (int nt = 0; nt < 2; ++nt)
            #pragma unroll
            for (int t = 0; t < 3; ++t)
                #pragma unroll
                for (int r2 = 0; r2 < 4; ++r2) d[(nt * 3 + t) * 4 + r2] = pacc[nt][t][r2];
    }
    __syncthreads();
    if (!(wh & 1)) {
        const float* d = mrgb + ((size_t)(wh >> 1) * 64 + lane) * 24;
        #pragma unroll
        for (int nt = 0; nt < 2; ++nt)
            #pragma unroll
            for (int t = 0; t < 3; ++t)
                #pragma unroll
                for (int r2 = 0; r2 < 4; ++r2) pacc[nt][t][r2] += d[(nt * 3 + t) * 4 + r2];
    }
    __syncthreads();
    if (wh == 2) {
        float* d = mrgb + (size_t)lane * 24;
        #pragma unroll
        for (int nt = 0; nt < 2; ++nt)
            #pragma unroll
            for (int t = 0; t < 3; ++t)
                #pragma unroll
                for (int r2 = 0; r2 < 4; ++r2) d[(nt * 3 + t) * 4 + r2] = pacc[nt][t][r2];
    }
    __syncthreads();
    if (wh == 0) {
        const float* d = mrgb + (size_t)lane * 24;
        #pragma unroll
        for (int nt = 0; nt < 2; ++nt)
            #pragma unroll
            for (int t = 0; t < 3; ++t)
                #pragma unroll
                for (int r2 = 0; r2 < 4; ++r2) pacc[nt][t][r2] += d[(nt * 3 + t) * 4 + r2];

        // comb = feat + attended/ps + 0.1*prop/ps  -> combT (LDS)
        #pragma unroll
        for (int nt = 0; nt < 2; ++nt) {
            float psn = __shfl(pacc[nt][2][1], nl);   // ones-row (h=33): g4==0, reg 1
            float prn = __shfl(pacc[nt][2][0], nl);   // ds-row   (h=32): g4==0, reg 0
            float invS = 1.f / psn;
            float pp = prn * invS * 0.1f;
            size_t o = ((size_t)b * Nn + n0w + nt * 16 + nl) * Hh;
            #pragma unroll
            for (int t = 0; t < 2; ++t) {
                f4 fv = *(const f4*)(feat + o + t * 16 + g4 * 4);
                #pragma unroll
                for (int r2 = 0; r2 < 4; ++r2)
                    combT[nt * 16 + nl][t * 16 + g4 * 4 + r2] = fv[r2] + pacc[nt][t][r2] * invS + pp;
            }
        }
    }
    __syncthreads();

    // ---- fused output projection + LayerNorm (each wave: 8 rows) ----
    int h = lane & 31;
    #pragma unroll
    for (int pass = 0; pass < 4; ++pass) {
        int row = wh * 8 + pass * 2 + (lane >> 5);
        float a = gbb[0][h];
        #pragma unroll
        for (int k = 0; k < Hh; ++k) a += combT[row][k] * WoT[k][h];
        float mu = a;
        #pragma unroll
        for (int w = 1; w < 32; w <<= 1) mu += __shfl_xor(mu, w);
        mu *= (1.f / 32.f);
        float dd = a - mu;
        float v = dd * dd;
        #pragma unroll
        for (int w = 1; w < 32; w <<= 1) v += __shfl_xor(v, w);
        v *= (1.f / 32.f);
        out[((size_t)b * Nn + n0w + row) * Hh + h] =
            dd * rsqrtf(v + LN_EPS) * gbb[1][h] + gbb[2][h];
    }
}

extern "C" void kernel_launch(void* const* d_in, const int* in_sizes, int n_in,
                              void* d_out, int out_size, void* d_ws, size_t ws_size,
                              hipStream_t stream) {
    const float* x     = (const float*)d_in[0];
    const float* feat  = (const float*)d_in[1];
    const float* dlog  = (const float*)d_in[2];
    const float* Wq    = (const float*)d_in[3];
    const float* bq    = (const float*)d_in[4];
    const float* Wk    = (const float*)d_in[5];
    const float* bk    = (const float*)d_in[6];
    const float* Wv    = (const float*)d_in[7];
    const float* bv    = (const float*)d_in[8];
    const float* adj   = (const float*)d_in[9];
    const float* geo   = (const float*)d_in[10];
    const float* Wo    = (const float*)d_in[11];
    const float* bo    = (const float*)d_in[12];
    const float* gamma = (const float*)d_in[13];
    const float* beta  = (const float*)d_in[14];
    float* out = (float*)d_out;

    char* w = (char*)d_ws;
    unsigned short* Qbf  = (unsigned short*)w;  w += (size_t)Bb * Nn * Hh * 2;
    unsigned short* Kf   = (unsigned short*)w;  w += (size_t)Bb * Nn * Hh * 2;
    unsigned short* Vf   = (unsigned short*)w;  w += (size_t)Bb * 98304 * 2;   // 48-row frag
    unsigned short* adjF = (unsigned short*)w;  w += (size_t)Nn * Nn * 2;

    k_adjprep<<<512, 256, 0, stream>>>(adj, geo, adjF);
    k_qkv<<<Bb * Nn / 8, 256, 0, stream>>>(feat, x, dlog, Wq, bq, Wk, bk, Wv, bv, geo,
                                           Qbf, Kf, Vf);
    k_attn<<<1024, 256, 0, stream>>>(Qbf, Kf, Vf, adjF, feat, Wo, bo, gamma, beta, out);
}

// Round 18
// 53.620 us; speedup vs baseline: 1.4298x; 1.0064x over previous
//
#include <hip/hip_runtime.h>
#include <hip/hip_bf16.h>
#include <math.h>
#include <stdint.h>

#define Bb 16
#define Tt 28
#define Nn 2048
#define Hh 32
#define LAGS 8
#define LN_EPS 1e-5f
#define PSTR 56                      // P row stride (shorts): 2-way banks on b128/b64

typedef float f4 __attribute__((ext_vector_type(4)));
typedef short s8v __attribute__((ext_vector_type(8)));
typedef unsigned short u16x4 __attribute__((ext_vector_type(4)));
typedef unsigned short u16x8 __attribute__((ext_vector_type(8)));

__device__ __forceinline__ float b2f(unsigned short u) {
    union { unsigned uu; float ff; } x; x.uu = ((unsigned)u) << 16; return x.ff;
}
__device__ __forceinline__ unsigned short f2b(float f) {
    unsigned u = __float_as_uint(f);
    u += 0x7FFFu + ((u >> 16) & 1u);   // RNE
    return (unsigned short)(u >> 16);
}
__device__ __forceinline__ unsigned packbf2(float lo, float hi) {
    __hip_bfloat162 h = __float22bfloat162_rn(make_float2(lo, hi));
    union { __hip_bfloat162 h2; unsigned u; } c; c.h2 = h; return c.u;
}

// ---------- adj fp32 -> bf16 scaled by geo*5, fragment-tile layout ----------
// adjF[((n>>4)*512 + (m>>2))*64 + (n&15)*4 + (m&3)]
__global__ void k_adjprep(const float* __restrict__ adj, const float* __restrict__ geo_w,
                          unsigned short* __restrict__ adjF) {
    __shared__ float T[16][516];
    float geo = 1.f / (1.f + __expf(-geo_w[0]));
    float cg = geo * 5.f;
    int tid = threadIdx.x;
    int g = blockIdx.x >> 2, q = blockIdx.x & 3;
    int n0 = g * 16, m0 = q * 512;
    #pragma unroll
    for (int r = 0; r < 16; ++r) {
        T[r][tid] = adj[(size_t)(n0 + r) * Nn + m0 + tid];
        T[r][tid + 256] = adj[(size_t)(n0 + r) * Nn + m0 + tid + 256];
    }
    __syncthreads();
    unsigned short* region = adjF + ((size_t)g * 512 + q * 128) * 64;
    #pragma unroll
    for (int i = 0; i < 4; ++i) {
        int e0 = (i * 256 + tid) * 8;
        u16x8 w;
        #pragma unroll
        for (int j = 0; j < 8; ++j) {
            int e = e0 + j;
            int mq = e >> 6, nl = (e >> 2) & 15, mm = e & 3;
            w[j] = f2b(cg * T[nl][mq * 4 + mm]);
        }
        *(u16x8*)(region + e0) = w;
    }
}

// ---------- fused QKV + delayed-signal: Q prescaled by cs; K frag; V 48-row frag ----
// Kf[((b*128+(m>>4))*4+(k>>3))*16+(m&15)][8]        -> 65536 shorts/batch
// Vf[((b*64+(m>>5))*4+((m>>3)&3))*48 + h][8], h<48  -> 98304 shorts/batch
//   rows 0..31 = V^T, row 32 = delayed signal, row 33 = 1.0, rows 34..47 = 0
__global__ void k_qkv(const float* __restrict__ feat, const float* __restrict__ x,
                      const float* __restrict__ dlog,
                      const float* __restrict__ Wq, const float* __restrict__ bq,
                      const float* __restrict__ Wk, const float* __restrict__ bk,
                      const float* __restrict__ Wv, const float* __restrict__ bv,
                      const float* __restrict__ geo_w,
                      unsigned short* __restrict__ Qbf, unsigned short* __restrict__ Kf,
                      unsigned short* __restrict__ Vf) {
    __shared__ float WqT[Hh][Hh + 1], WkT[Hh][Hh + 1], WvT[Hh][Hh + 1];
    __shared__ float f[8][Hh];
    __shared__ __align__(16) unsigned short VT8[Hh][8];
    __shared__ __align__(16) unsigned short DS8[8];
    int tid = threadIdx.x;
    for (int i = tid; i < Hh * Hh; i += 256) {
        int h = i >> 5, k = i & 31;
        WqT[k][h] = Wq[i];
        WkT[k][h] = Wk[i];
        WvT[k][h] = Wv[i];
    }
    int n0 = blockIdx.x * 8;
    int b = n0 >> 11, mloc0 = n0 & 2047;
    // ---- delayed signal for this 8-row octet (wave 0 only) ----
    if (tid < 64) {
        float mx = -1e30f;
        #pragma unroll
        for (int t = 0; t < LAGS; ++t) mx = fmaxf(mx, dlog[t]);
        float s = 0.f, wv[LAGS];
        #pragma unroll
        for (int t = 0; t < LAGS; ++t) { wv[t] = __expf(dlog[t] - mx); s += wv[t]; }
        int t = tid >> 3, j = tid & 7;
        float dsv = (wv[t] / s) * x[(size_t)b * Tt * Nn + (size_t)(Tt - 1 - t) * Nn + mloc0 + j];
        dsv += __shfl_xor(dsv, 8);
        dsv += __shfl_xor(dsv, 16);
        dsv += __shfl_xor(dsv, 32);
        if (tid < 8) DS8[tid] = f2b(dsv);
    }
    float geo = 1.f / (1.f + __expf(-geo_w[0]));
    float cs = (1.f - geo) * 0.17677669529663687f;   // (1-geo)/sqrt(32)
    f[tid >> 5][tid & 31] = feat[(size_t)n0 * Hh + tid];
    __syncthreads();
    int lr = tid >> 5, h = tid & 31;
    float aq = bq[h], ak = bk[h], av = bv[h];
    #pragma unroll
    for (int k = 0; k < Hh; ++k) {
        float fv = f[lr][k];
        aq += fv * WqT[k][h];
        ak += fv * WkT[k][h];
        av += fv * WvT[k][h];
    }
    Qbf[(size_t)(n0 + lr) * Hh + h] = f2b(aq * cs);
    int mloc = mloc0 + lr;
    size_t kaddr = ((((size_t)b * 128 + (mloc >> 4)) * 4 + (h >> 3)) * 16 + (mloc & 15)) * 8 + (h & 7);
    Kf[kaddr] = f2b(ak);
    VT8[h][lr] = f2b(av);
    __syncthreads();
    size_t vbase = (((size_t)b * 64 + (mloc0 >> 5)) * 4 + ((mloc0 >> 3) & 3)) * 48;
    if (tid < 32) {
        *(u16x8*)(Vf + (vbase + tid) * 8) = *(const u16x8*)&VT8[tid][0];
    } else if (tid < 48) {
        int rr = tid - 32;            // 0=ds, 1=ones, 2..15=zero
        u16x8 wv8;
        if (rr == 0) {
            wv8 = *(const u16x8*)&DS8[0];
        } else {
            unsigned short fill = (rr == 1) ? (unsigned short)0x3F80 : (unsigned short)0;
            for (int j = 0; j < 8; ++j) wv8[j] = fill;
        }
        *(u16x8*)(Vf + (vbase + 32 + rr) * 8) = wv8;
    }
}

// ---------------- MFMA attention + fused output-proj + LayerNorm ------------------
// 4 waves/block, 32 n-cols, wave wh owns 32-m quarter of each 128-chunk.
// Software-pipelined: readP(c-1) -> loads(c+1) -> QK+SM(c) -> PV(c-1).
// Double per-wave P buffer removes the ds_write->ds_read turnaround from the chain.
__global__ __launch_bounds__(256, 2)
void k_attn(const unsigned short* __restrict__ Qbf,
            const unsigned short* __restrict__ Kf,
            const unsigned short* __restrict__ Vf,
            const unsigned short* __restrict__ adjF,
            const float* __restrict__ feat,
            const float* __restrict__ Wo, const float* __restrict__ bo,
            const float* __restrict__ gamma, const float* __restrict__ beta,
            float* __restrict__ out) {
    __shared__ __align__(16) unsigned short Pt[4][2][32 * PSTR];  // 28672 B; merge scratch later
    __shared__ float WoT[Hh][Hh + 1];
    __shared__ float combT[32][Hh + 1];
    __shared__ float gbb[3][Hh];

    int tid = threadIdx.x;
    int wid = tid >> 6, lane = tid & 63;
    int nl = lane & 15, g4 = lane >> 4;
    int wh = wid;

    for (int i = tid; i < Hh * Hh; i += 256) WoT[i & 31][i >> 5] = Wo[i];
    if (tid < 32) { gbb[0][tid] = bo[tid]; gbb[1][tid] = gamma[tid]; gbb[2][tid] = beta[tid]; }

    // XCD-partitioned swizzle: xcd = bid&7 -> (n-quarter = xcd>>1, batch-half = xcd&1)
    int bid = blockIdx.x;
    int xcd = bid & 7, r = bid >> 3;            // r: 0..127
    int b = ((xcd & 1) << 3) + (r & 7);
    int nt32 = ((xcd >> 1) << 4) + (r >> 3);    // 0..63
    int n0w = nt32 * 32;

    // Q B-fragments (col = n = nl, k = g4*8+j); Q pre-scaled by cs
    s8v qf[2];
    #pragma unroll
    for (int nt = 0; nt < 2; ++nt)
        qf[nt] = *(const s8v*)(Qbf + (((size_t)b * Nn + n0w + nt * 16 + nl) << 5) + g4 * 8);

    f4 pacc[2][3];
    #pragma unroll
    for (int nt = 0; nt < 2; ++nt)
        #pragma unroll
        for (int t = 0; t < 3; ++t) pacc[nt][t] = (f4){0.f, 0.f, 0.f, 0.f};

    const unsigned short* Kb = Kf + (size_t)b * 65536;
    const unsigned short* Vb = Vf + (size_t)b * 98304;
    unsigned short* Pw0 = Pt[wid][0];
    unsigned short* Pw1 = Pt[wid][1];

    // pointer-bump bases (chunk 0, this wave's 32-m window)
    const unsigned short* pK  = Kb + (((size_t)(wh * 2) * 4 + g4) * 16 + nl) * 8;
    const unsigned short* pV  = Vb + (((size_t)wh * 4 + g4) * 48 + nl) * 8;
    const unsigned short* pA0 = adjF + ((size_t)(nt32 * 2) * 512 + wh * 8 + g4) * 64 + nl * 4;
    const unsigned short* pA1 = adjF + ((size_t)(nt32 * 2 + 1) * 512 + wh * 8 + g4) * 64 + nl * 4;

    struct Frag {
        s8v kf0, kf1, vf0, vf1, vf2;
        u16x4 a00, a01, a10, a11;
    };

    auto loadP = [&](Frag& F) {
        F.kf0 = *(const s8v*)(pK);
        F.kf1 = *(const s8v*)(pK + 512);
        F.vf0 = *(const s8v*)(pV);
        F.vf1 = *(const s8v*)(pV + 128);
        F.vf2 = *(const s8v*)(pV + 256);
        F.a00 = *(const u16x4*)(pA0);
        F.a01 = *(const u16x4*)(pA0 + 256);
        F.a10 = *(const u16x4*)(pA1);
        F.a11 = *(const u16x4*)(pA1 + 256);
        pK += 4096;
        pV += 6144;
        pA0 += 2048;
        pA1 += 2048;
    };

    auto mkC = [&](u16x4 av) -> f4 {
        f4 C;
        C[0] = b2f(av[0]); C[1] = b2f(av[1]); C[2] = b2f(av[2]); C[3] = b2f(av[3]);
        return C;
    };

    auto SM = [&](f4 sc, int nt, int mg, unsigned short* Pw) {
        float p0 = __expf(sc[0]), p1 = __expf(sc[1]);
        float p2 = __expf(sc[2]), p3 = __expf(sc[3]);
        uint2 w;
        w.x = packbf2(p0, p1);
        w.y = packbf2(p2, p3);
        *(uint2*)(Pw + (size_t)(nt * 16 + nl) * PSTR + mg * 16 + g4 * 4) = w;
    };

    auto qks = [&](Frag& F, unsigned short* Pw) {
        f4 sc00 = __builtin_amdgcn_mfma_f32_16x16x32_bf16(F.kf0, qf[0], mkC(F.a00), 0, 0, 0);
        f4 sc01 = __builtin_amdgcn_mfma_f32_16x16x32_bf16(F.kf1, qf[0], mkC(F.a01), 0, 0, 0);
        f4 sc10 = __builtin_amdgcn_mfma_f32_16x16x32_bf16(F.kf0, qf[1], mkC(F.a10), 0, 0, 0);
        f4 sc11 = __builtin_amdgcn_mfma_f32_16x16x32_bf16(F.kf1, qf[1], mkC(F.a11), 0, 0, 0);
        SM(sc00, 0, 0, Pw);
        SM(sc01, 0, 1, Pw);
        SM(sc10, 1, 0, Pw);
        SM(sc11, 1, 1, Pw);
    };

    auto readP = [&](const unsigned short* Pw, s8v& pb0, s8v& pb1) {
        pb0 = *(const s8v*)(Pw + (size_t)(0 * 16 + nl) * PSTR + g4 * 8);
        pb1 = *(const s8v*)(Pw + (size_t)(1 * 16 + nl) * PSTR + g4 * 8);
    };

    auto pvm = [&](s8v v0, s8v v1, s8v v2, s8v pb0, s8v pb1) {
        pacc[0][0] = __builtin_amdgcn_mfma_f32_16x16x32_bf16(v0, pb0, pacc[0][0], 0, 0, 0);
        pacc[0][1] = __builtin_amdgcn_mfma_f32_16x16x32_bf16(v1, pb0, pacc[0][1], 0, 0, 0);
        pacc[0][2] = __builtin_amdgcn_mfma_f32_16x16x32_bf16(v2, pb0, pacc[0][2], 0, 0, 0);
        pacc[1][0] = __builtin_amdgcn_mfma_f32_16x16x32_bf16(v0, pb1, pacc[1][0], 0, 0, 0);
        pacc[1][1] = __builtin_amdgcn_mfma_f32_16x16x32_bf16(v1, pb1, pacc[1][1], 0, 0, 0);
        pacc[1][2] = __builtin_amdgcn_mfma_f32_16x16x32_bf16(v2, pb1, pacc[1][2], 0, 0, 0);
    };

    const int NC = Nn / 128;     // 16
    Frag A, B;
    s8v sv0, sv1, sv2, pb0, pb1;

    loadP(A);                    // chunk 0
    loadP(B);                    // chunk 1 (in flight)
    qks(A, Pw0);                 // QK+SM chunk 0 -> P0
    sv0 = A.vf0; sv1 = A.vf1; sv2 = A.vf2;

    for (int i = 0; i < (NC - 2) / 2; ++i) {   // i = 0..6 : chunks 2i+1, 2i+2
        readP(Pw0, pb0, pb1);    // P(2i)  — written a full stage ago
        loadP(A);                // chunk 2i+2
        qks(B, Pw1);             // QK+SM chunk 2i+1 -> P(2i+1)
        pvm(sv0, sv1, sv2, pb0, pb1);          // PV chunk 2i
        sv0 = B.vf0; sv1 = B.vf1; sv2 = B.vf2;
        loadP(B);                // chunk 2i+3
        readP(Pw1, pb0, pb1);    // P(2i+1) — write has pvm+loadP of cover
        qks(A, Pw0);             // QK+SM chunk 2i+2 -> P(2i+2)
        pvm(sv0, sv1, sv2, pb0, pb1);          // PV chunk 2i+1
        sv0 = A.vf0; sv1 = A.vf1; sv2 = A.vf2;
    }
    // epilogue: chunks NC-2 (in A, P in Pw0) and NC-1 (in B)
    readP(Pw0, pb0, pb1);        // P(NC-2)
    qks(B, Pw1);                 // QK+SM chunk NC-1 -> P(NC-1)
    pvm(sv0, sv1, sv2, pb0, pb1);              // PV chunk NC-2
    sv0 = B.vf0; sv1 = B.vf1; sv2 = B.vf2;
    readP(Pw1, pb0, pb1);        // P(NC-1)
    pvm(sv0, sv1, sv2, pb0, pb1);              // PV chunk NC-1

    // ---- linear merge of pacc (24 floats/lane) across the 4 wh waves ----
    float* mrgb = (float*)&Pt[0][0][0];   // 2 regions x 64 lanes x 24 floats = 12288 B <= 28672
    __syncthreads();                      // all PV reads of Pt done
    if (wh & 1) {
        float* d = mrgb + ((size_t)(wh >> 1) * 64 + lane) * 24;
        #pragma unroll
        for (int nt = 0; nt < 2; ++nt)
            #pragma unroll
            for (int t = 0; t < 3; ++t)
                #pragma unroll
                for (int r2 = 0; r2 < 4; ++r2) d[(nt * 3 + t) * 4 + r2] = pacc[nt][t][r2];
    }
    __syncthreads();
    if (!(wh & 1)) {
        const float* d = mrgb + ((size_t)(wh >> 1) * 64 + lane) * 24;
        #pragma unroll
        for (int nt = 0; nt < 2; ++nt)
            #pragma unroll
            for (int t = 0; t < 3; ++t)
                #pragma unroll
                for (int r2 = 0; r2 < 4; ++r2) pacc[nt][t][r2] += d[(nt * 3 + t) * 4 + r2];
    }
    __syncthreads();
    if (wh == 2) {
        float* d = mrgb + (size_t)lane * 24;
        #pragma unroll
        for (int nt = 0; nt < 2; ++nt)
            #pragma unroll
            for (int t = 0; t < 3; ++t)
                #pragma unroll
                for (int r2 = 0; r2 < 4; ++r2) d[(nt * 3 + t) * 4 + r2] = pacc[nt][t][r2];
    }
    __syncthreads();
    if (wh == 0) {
        const float* d = mrgb + (size_t)lane * 24;
        #pragma unroll
        for (int nt = 0; nt < 2; ++nt)
            #pragma unroll
            for (int t = 0; t < 3; ++t)
                #pragma unroll
                for (int r2 = 0; r2 < 4; ++r2) pacc[nt][t][r2] += d[(nt * 3 + t) * 4 + r2];

        // comb = feat + attended/ps + 0.1*prop/ps  -> combT (LDS)
        #pragma unroll
        for (int nt = 0; nt < 2; ++nt) {
            float psn = __shfl(pacc[nt][2][1], nl);   // ones-row (h=33): g4==0, reg 1
            float prn = __shfl(pacc[nt][2][0], nl);   // ds-row   (h=32): g4==0, reg 0
            float invS = 1.f / psn;
            float pp = prn * invS * 0.1f;
            size_t o = ((size_t)b * Nn + n0w + nt * 16 + nl) * Hh;
            #pragma unroll
            for (int t = 0; t < 2; ++t) {
                f4 fv = *(const f4*)(feat + o + t * 16 + g4 * 4);
                #pragma unroll
                for (int r2 = 0; r2 < 4; ++r2)
                    combT[nt * 16 + nl][t * 16 + g4 * 4 + r2] = fv[r2] + pacc[nt][t][r2] * invS + pp;
            }
        }
    }
    __syncthreads();

    // ---- fused output projection + LayerNorm (each wave: 8 rows) ----
    int h = lane & 31;
    #pragma unroll
    for (int pass = 0; pass < 4; ++pass) {
        int row = wh * 8 + pass * 2 + (lane >> 5);
        float a = gbb[0][h];
        #pragma unroll
        for (int k = 0; k < Hh; ++k) a += combT[row][k] * WoT[k][h];
        float mu = a;
        #pragma unroll
        for (int w = 1; w < 32; w <<= 1) mu += __shfl_xor(mu, w);
        mu *= (1.f / 32.f);
        float dd = a - mu;
        float v = dd * dd;
        #pragma unroll
        for (int w = 1; w < 32; w <<= 1) v += __shfl_xor(v, w);
        v *= (1.f / 32.f);
        out[((size_t)b * Nn + n0w + row) * Hh + h] =
            dd * rsqrtf(v + LN_EPS) * gbb[1][h] + gbb[2][h];
    }
}

extern "C" void kernel_launch(void* const* d_in, const int* in_sizes, int n_in,
                              void* d_out, int out_size, void* d_ws, size_t ws_size,
                              hipStream_t stream) {
    const float* x     = (const float*)d_in[0];
    const float* feat  = (const float*)d_in[1];
    const float* dlog  = (const float*)d_in[2];
    const float* Wq    = (const float*)d_in[3];
    const float* bq    = (const float*)d_in[4];
    const float* Wk    = (const float*)d_in[5];
    const float* bk    = (const float*)d_in[6];
    const float* Wv    = (const float*)d_in[7];
    const float* bv    = (const float*)d_in[8];
    const float* adj   = (const float*)d_in[9];
    const float* geo   = (const float*)d_in[10];
    const float* Wo    = (const float*)d_in[11];
    const float* bo    = (const float*)d_in[12];
    const float* gamma = (const float*)d_in[13];
    const float* beta  = (const float*)d_in[14];
    float* out = (float*)d_out;

    char* w = (char*)d_ws;
    unsigned short* Qbf  = (unsigned short*)w;  w += (size_t)Bb * Nn * Hh * 2;
    unsigned short* Kf   = (unsigned short*)w;  w += (size_t)Bb * Nn * Hh * 2;
    unsigned short* Vf   = (unsigned short*)w;  w += (size_t)Bb * 98304 * 2;   // 48-row frag
    unsigned short* adjF = (unsigned short*)w;  w += (size_t)Nn * Nn * 2;

    k_adjprep<<<512, 256, 0, stream>>>(adj, geo, adjF);
    k_qkv<<<Bb * Nn / 8, 256, 0, stream>>>(feat, x, dlog, Wq, bq, Wk, bk, Wv, bv, geo,
                                           Qbf, Kf, Vf);
    k_attn<<<1024, 256, 0, stream>>>(Qbf, Kf, Vf, adjF, feat, Wo, bo, gamma, beta, out);
}